// Round 6
// baseline (1061.984 us; speedup 1.0000x reference)
//
#include <hip/hip_runtime.h>
#include <hip/hip_fp16.h>

// x[8192,4096] f32, w[16384,4096] f32, bias[16384] f32 -> out[8192,16384] f32
#define M_DIM 8192
#define K_DIM 4096
#define N_DIM 16384
#define NW_ELEMS (16384 * 4096)
#define NX_ELEMS (8192 * 4096)
#define NT 64   // K / 64

typedef _Float16 half8 __attribute__((ext_vector_type(8)));
typedef float f32x4 __attribute__((ext_vector_type(4)));

// ---------------- gamma = max(mean(|clip(w,-2,2)|), 1e-4), f64 accumulation ----------------

__global__ void zero_gsum(double* g) {
    if (threadIdx.x == 0 && blockIdx.x == 0) *g = 0.0;
}

__global__ void gamma_reduce(const float4* __restrict__ w4, double* __restrict__ gsum, int n4) {
    double acc = 0.0;
    int stride = gridDim.x * blockDim.x;
    for (int i = blockIdx.x * blockDim.x + threadIdx.x; i < n4; i += stride) {
        float4 v = w4[i];
        float s = fminf(fabsf(v.x), 2.0f) + fminf(fabsf(v.y), 2.0f) +
                  fminf(fabsf(v.z), 2.0f) + fminf(fabsf(v.w), 2.0f);
        acc += (double)s;
    }
    int lane = threadIdx.x & 63;
    int wid = threadIdx.x >> 6;
    #pragma unroll
    for (int off = 32; off > 0; off >>= 1) acc += __shfl_down(acc, off, 64);
    __shared__ double sred[4];
    if (lane == 0) sred[wid] = acc;
    __syncthreads();
    if (threadIdx.x == 0) atomicAdd(gsum, sred[0] + sred[1] + sred[2] + sred[3]);
}

// ---------------- quantize weight -> ternary f16 ----------------

__global__ void quant_w(const float4* __restrict__ w4, half8* __restrict__ wq,
                        const double* __restrict__ gsum) {
    double gamma = fmax(*gsum * (1.0 / (double)NW_ELEMS), 1e-4);
    double rg = 1.0 / gamma;
    int i = blockIdx.x * blockDim.x + threadIdx.x;
    float4 a = w4[2 * i];
    float4 b = w4[2 * i + 1];
    float vals[8] = {a.x, a.y, a.z, a.w, b.x, b.y, b.z, b.w};
    half8 q;
    #pragma unroll
    for (int j = 0; j < 8; j++) {
        float cv = fminf(fmaxf(vals[j], -2.0f), 2.0f);
        double t = rint((double)cv * rg);
        t = fmax(-1.0, fmin(1.0, t));
        q[j] = (_Float16)t;
    }
    wq[i] = q;
}

// ---------------- convert x -> f16 ----------------

__global__ void cvt_x(const float4* __restrict__ x4, half8* __restrict__ x16) {
    int i = blockIdx.x * blockDim.x + threadIdx.x;
    float4 a = x4[2 * i];
    float4 b = x4[2 * i + 1];
    half8 h;
    h[0] = (_Float16)a.x; h[1] = (_Float16)a.y; h[2] = (_Float16)a.z; h[3] = (_Float16)a.w;
    h[4] = (_Float16)b.x; h[5] = (_Float16)b.y; h[6] = (_Float16)b.z; h[7] = (_Float16)b.w;
    x16[i] = h;
}

// ---------------- 256x256 GEMM, barrier-straddling MFMA clusters ----------------
// 512 threads = 8 waves (2M x 4N). Per wave: 128x64 output = acc[8][4] f32x4.
// LDS: A buf0 @0, A buf1 @32768, B buf0 @65536, B buf1 @98304. XOR-swizzle
// slot^=(row&7) -> conflict-free ds_read_b128; base-ptr + imm addressing.
// Key idea: every barrier is immediately followed by a REGISTER-RESIDENT 16-MFMA
// cluster, so the post-barrier LDS read storm hides under MFMA:
//   head:  read b0[cur] | Q3_prev(a1xb1, regs) | read a1[cur] | Q0(a0xb0) | read b1[cur]
//   B1  :  vmcnt(4)+lgkmcnt(0)+barrier      (A(t+1) resident for ALL waves)
//   win2:  stage A(t+2) | Q1(a0xb1, regs) | read a0<-nxt | Q2(a1xb0) | stage B(t+2)
//   B2  :  vmcnt(8)+barrier                (B(t+1) resident for ALL waves)
// Q3 of the last tile runs after the loop. vmcnt ledger: entering tile t: 8
// outstanding {A(t+1),B(t+1)}; B1 waits to 4 (A done); win2 adds 8; B2 waits to 8.

__device__ inline void gload16(const _Float16* g, char* lds) {
    __builtin_amdgcn_global_load_lds((const __attribute__((address_space(1))) void*)g,
        (__attribute__((address_space(3))) void*)lds, 16, 0, 0);
}

#define MFMA16(a, b, c) __builtin_amdgcn_mfma_f32_16x16x32_f16(a, b, c, 0, 0, 0)

__global__ __launch_bounds__(512, 2) void gemm_kernel(
    const _Float16* __restrict__ A,   // x16 [M][K]
    const _Float16* __restrict__ B,   // wq  [N][K]
    const float* __restrict__ bias,
    const double* __restrict__ gsum,
    float* __restrict__ out) {
    __shared__ __align__(16) char sm[131072];

    const int tid = threadIdx.x;
    const int wid = tid >> 6;
    const int lane = tid & 63;
    const int fr = lane & 15;
    const int kg = lane >> 4;
    const int f7 = fr & 7;
    const int wm = wid >> 2;   // 0..1
    const int wn = wid & 3;    // 0..3

    // T1: bijective XCD swizzle (2048 % 8 == 0).
    const int orig = blockIdx.x;
    const int bm = ((orig & 7) << 2) + ((orig >> 3) & 3);
    const int bn = orig >> 5;
    const int m0 = bm << 8, n0 = bn << 8;

    // staging: linear LDS dest, inverse-swizzled global source (rule #21)
    const int srow = tid >> 3;
    const int ks8 = (((tid & 7) ^ (srow & 7)) << 3);
    const int poff = srow * K_DIM + ks8;
    const _Float16* Ab = A + (size_t)m0 * K_DIM + poff;
    const _Float16* Bb = B + (size_t)n0 * K_DIM + poff;
    const uint32_t dwave = (uint32_t)(wid << 10);

    #define STAGE_A(kt, bufb) do {                                              \
        _Pragma("unroll")                                                       \
        for (int _i = 0; _i < 4; ++_i)                                          \
            gload16(Ab + (_i * (64 * K_DIM) + (kt)),                            \
                    sm + (bufb) * 32768 + (_i << 13) + dwave);                  \
    } while (0)
    #define STAGE_B(kt, bufb) do {                                              \
        _Pragma("unroll")                                                       \
        for (int _i = 0; _i < 4; ++_i)                                          \
            gload16(Bb + (_i * (64 * K_DIM) + (kt)),                            \
                    sm + 65536 + (bufb) * 32768 + (_i << 13) + dwave);          \
    } while (0)

    // base pointers carrying the lane-dependent swizzle; all reads = base + imm
    const char* const smc = sm;
    const char* const pA0 = smc + ((wm * 128 + fr) << 7) + ((kg ^ f7) << 4);
    const char* const pA1 = smc + ((wm * 128 + fr) << 7) + (((4 | kg) ^ f7) << 4);
    const char* const pB0 = smc + 65536 + ((wn * 64 + fr) << 7) + ((kg ^ f7) << 4);
    const char* const pB1 = smc + 65536 + ((wn * 64 + fr) << 7) + (((4 | kg) ^ f7) << 4);

    f32x4 acc[8][4] = {};
    half8 a0[4][2], a1[4][2], b0[2][2], b1[2][2];

    // prologue: tile 0 -> buf0, tile 1 -> buf1; wait tile 0; prime a0 of tile 0
    STAGE_A(0, 0); STAGE_B(0, 0);
    STAGE_A(64, 1); STAGE_B(64, 1);
    asm volatile("s_waitcnt vmcnt(8)" ::: "memory");
    __builtin_amdgcn_s_barrier();
    asm volatile("" ::: "memory");
    __builtin_amdgcn_sched_barrier(0);
    #pragma unroll
    for (int i = 0; i < 4; ++i) {
        a0[i][0] = *(const half8*)(pA0 + i * 2048);
        a0[i][1] = *(const half8*)(pA1 + i * 2048);
    }

    #define TILE(T_, CUR_, NXT_, HQ3_) do {                                       \
        const int _kt2 = ((T_) + 2) << 6;                                         \
        const bool _st = ((T_) < NT - 2);                                         \
        const bool _rd = ((T_) < NT - 1);                                         \
        /* ---- head: read b0; Q3 of PREVIOUS tile (register-resident) ---- */    \
        _Pragma("unroll")                                                         \
        for (int j = 0; j < 2; ++j) {                                             \
            b0[j][0] = *(const half8*)(pB0 + ((CUR_) * 32768 + j * 2048));        \
            b0[j][1] = *(const half8*)(pB1 + ((CUR_) * 32768 + j * 2048));        \
        }                                                                         \
        if (HQ3_) {                                                               \
            __builtin_amdgcn_s_setprio(1);                                        \
            _Pragma("unroll")                                                     \
            for (int i = 0; i < 4; ++i)                                           \
                _Pragma("unroll")                                                 \
                for (int j = 0; j < 2; ++j) {                                     \
                    acc[4 + i][2 + j] = MFMA16(a1[i][0], b1[j][0], acc[4 + i][2 + j]); \
                    acc[4 + i][2 + j] = MFMA16(a1[i][1], b1[j][1], acc[4 + i][2 + j]); \
                }                                                                 \
            __builtin_amdgcn_s_setprio(0);                                        \
        }                                                                         \
        /* ---- read a1 (clobbers prev a1 AFTER Q3 consumed it) ---- */           \
        _Pragma("unroll")                                                         \
        for (int i = 0; i < 4; ++i) {                                             \
            a1[i][0] = *(const half8*)(pA0 + ((CUR_) * 32768 + (4 + i) * 2048));  \
            a1[i][1] = *(const half8*)(pA1 + ((CUR_) * 32768 + (4 + i) * 2048));  \
        }                                                                         \
        /* ---- Q0: a0 x b0 ---- */                                               \
        __builtin_amdgcn_s_setprio(1);                                            \
        _Pragma("unroll")                                                         \
        for (int i = 0; i < 4; ++i)                                               \
            _Pragma("unroll")                                                     \
            for (int j = 0; j < 2; ++j) {                                         \
                acc[i][j] = MFMA16(a0[i][0], b0[j][0], acc[i][j]);                \
                acc[i][j] = MFMA16(a0[i][1], b0[j][1], acc[i][j]);                \
            }                                                                     \
        __builtin_amdgcn_s_setprio(0);                                            \
        /* ---- read b1 ---- */                                                   \
        _Pragma("unroll")                                                         \
        for (int j = 0; j < 2; ++j) {                                             \
            b1[j][0] = *(const half8*)(pB0 + ((CUR_) * 32768 + (2 + j) * 2048));  \
            b1[j][1] = *(const half8*)(pB1 + ((CUR_) * 32768 + (2 + j) * 2048));  \
        }                                                                         \
        /* ---- B1: buf[cur] reads drained; A(t+1) resident everywhere ---- */    \
        asm volatile("s_waitcnt vmcnt(4) lgkmcnt(0)" ::: "memory");               \
        __builtin_amdgcn_sched_barrier(0);                                        \
        __builtin_amdgcn_s_barrier();                                             \
        asm volatile("" ::: "memory");                                            \
        __builtin_amdgcn_sched_barrier(0);                                        \
        /* ---- win2: stage A(t+2); Q1 (regs); read a0<-nxt; Q2; stage B ---- */  \
        if (_st) STAGE_A(_kt2, CUR_);                                             \
        __builtin_amdgcn_s_setprio(1);                                            \
        _Pragma("unroll")                                                         \
        for (int i = 0; i < 4; ++i)                                               \
            _Pragma("unroll")                                                     \
            for (int j = 0; j < 2; ++j) {                                         \
                acc[i][2 + j] = MFMA16(a0[i][0], b1[j][0], acc[i][2 + j]);        \
                acc[i][2 + j] = MFMA16(a0[i][1], b1[j][1], acc[i][2 + j]);        \
            }                                                                     \
        __builtin_amdgcn_s_setprio(0);                                            \
        if (_rd) {                                                                \
            _Pragma("unroll")                                                     \
            for (int i = 0; i < 4; ++i) {                                         \
                a0[i][0] = *(const half8*)(pA0 + ((NXT_) * 32768 + i * 2048));    \
                a0[i][1] = *(const half8*)(pA1 + ((NXT_) * 32768 + i * 2048));    \
            }                                                                     \
        }                                                                         \
        __builtin_amdgcn_s_setprio(1);                                            \
        _Pragma("unroll")                                                         \
        for (int i = 0; i < 4; ++i)                                               \
            _Pragma("unroll")                                                     \
            for (int j = 0; j < 2; ++j) {                                         \
                acc[4 + i][j] = MFMA16(a1[i][0], b0[j][0], acc[4 + i][j]);        \
                acc[4 + i][j] = MFMA16(a1[i][1], b0[j][1], acc[4 + i][j]);        \
            }                                                                     \
        __builtin_amdgcn_s_setprio(0);                                            \
        if (_st) STAGE_B(_kt2, CUR_);                                             \
        /* ---- B2: B(t+1) resident everywhere; Q3 deferred past barrier ---- */  \
        if (_st) {                                                                \
            asm volatile("s_waitcnt vmcnt(8)" ::: "memory");                      \
        } else if ((T_) == NT - 2) {                                              \
            asm volatile("s_waitcnt vmcnt(0)" ::: "memory");                      \
        }                                                                         \
        __builtin_amdgcn_sched_barrier(0);                                        \
        __builtin_amdgcn_s_barrier();                                             \
        asm volatile("" ::: "memory");                                            \
        __builtin_amdgcn_sched_barrier(0);                                        \
    } while (0)

    TILE(0, 0, 1, 0);
    TILE(1, 1, 0, 1);
    for (int t = 2; t < NT; t += 2) {
        TILE(t, 0, 1, 1);
        TILE(t + 1, 1, 0, 1);
    }
    // final Q3 (tile NT-1's a1 x b1)
    #pragma unroll
    for (int i = 0; i < 4; ++i)
        #pragma unroll
        for (int j = 0; j < 2; ++j) {
            acc[4 + i][2 + j] = MFMA16(a1[i][0], b1[j][0], acc[4 + i][2 + j]);
            acc[4 + i][2 + j] = MFMA16(a1[i][1], b1[j][1], acc[4 + i][2 + j]);
        }

    // ---- epilogue: out = acc*gamma + bias. C/D: col = fr, row = kg*4 + jj ----
    const float gamma = (float)fmax(*gsum * (1.0 / (double)NW_ELEMS), 1e-4);
    const int rbase = m0 + wm * 128 + (kg << 2);
    #pragma unroll
    for (int j = 0; j < 4; ++j) {
        const int gn = n0 + wn * 64 + j * 16 + fr;
        const float bv = bias[gn];
        #pragma unroll
        for (int i = 0; i < 8; ++i) {
            #pragma unroll
            for (int jj = 0; jj < 4; ++jj) {
                const int gm = rbase + i * 16 + jj;
                out[(size_t)gm * N_DIM + gn] = acc[i][j][jj] * gamma + bv;
            }
        }
    }
}

// ---------------- launch ----------------

extern "C" void kernel_launch(void* const* d_in, const int* in_sizes, int n_in,
                              void* d_out, int out_size, void* d_ws, size_t ws_size,
                              hipStream_t stream) {
    const float* x = (const float*)d_in[0];
    const float* w = (const float*)d_in[1];
    const float* bias = (const float*)d_in[2];
    float* out = (float*)d_out;

    char* ws = (char*)d_ws;
    double* gsum = (double*)ws;
    _Float16* x16 = (_Float16*)(ws + 256);
    _Float16* w16 = (_Float16*)(ws + 256 + (size_t)NX_ELEMS * 2);

    zero_gsum<<<1, 1, 0, stream>>>(gsum);
    gamma_reduce<<<2048, 256, 0, stream>>>((const float4*)w, gsum, NW_ELEMS / 4);
    quant_w<<<NW_ELEMS / 8 / 256, 256, 0, stream>>>((const float4*)w, (half8*)w16, gsum);
    cvt_x<<<NX_ELEMS / 8 / 256, 256, 0, stream>>>((const float4*)x, (half8*)x16);

    const int nblk = (M_DIM / 256) * (N_DIM / 256);   // 2048
    gemm_kernel<<<nblk, 512, 0, stream>>>(x16, w16, bias, gsum, out);
}

// Round 7
// 720.463 us; speedup vs baseline: 1.4740x; 1.4740x over previous
//
#include <hip/hip_runtime.h>

// x[8192,4096] f32, w[16384,4096] f32, bias[16384] f32 -> out[8192,16384] f32
#define M_DIM 8192
#define K_DIM 4096
#define N_DIM 16384
#define NW_ELEMS (16384 * 4096)
#define NX_ELEMS (8192 * 4096)
#define NT 32   // K / 128 (BK=128 i8)

typedef int int4x __attribute__((ext_vector_type(4)));

// ---------------- scalars: gsum (f64) and xmax (f32-as-int bits) ----------------

__global__ void zero_scalars(double* g, int* xm) {
    if (threadIdx.x == 0 && blockIdx.x == 0) { *g = 0.0; *xm = 0; }
}

// gamma = max(mean(|clip(w,-2,2)|), 1e-4), f64 accumulation
__global__ void gamma_reduce(const float4* __restrict__ w4, double* __restrict__ gsum, int n4) {
    double acc = 0.0;
    int stride = gridDim.x * blockDim.x;
    for (int i = blockIdx.x * blockDim.x + threadIdx.x; i < n4; i += stride) {
        float4 v = w4[i];
        float s = fminf(fabsf(v.x), 2.0f) + fminf(fabsf(v.y), 2.0f) +
                  fminf(fabsf(v.z), 2.0f) + fminf(fabsf(v.w), 2.0f);
        acc += (double)s;
    }
    int lane = threadIdx.x & 63;
    int wid = threadIdx.x >> 6;
    #pragma unroll
    for (int off = 32; off > 0; off >>= 1) acc += __shfl_down(acc, off, 64);
    __shared__ double sred[4];
    if (lane == 0) sred[wid] = acc;
    __syncthreads();
    if (threadIdx.x == 0) atomicAdd(gsum, sred[0] + sred[1] + sred[2] + sred[3]);
}

// absmax(x): positive-float int bits are monotonic -> atomicMax on int
__global__ void xmax_reduce(const float4* __restrict__ x4, int* __restrict__ xmb, int n4) {
    float m = 0.0f;
    int stride = gridDim.x * blockDim.x;
    for (int i = blockIdx.x * blockDim.x + threadIdx.x; i < n4; i += stride) {
        float4 v = x4[i];
        m = fmaxf(m, fmaxf(fmaxf(fabsf(v.x), fabsf(v.y)), fmaxf(fabsf(v.z), fabsf(v.w))));
    }
    int lane = threadIdx.x & 63;
    int wid = threadIdx.x >> 6;
    #pragma unroll
    for (int off = 32; off > 0; off >>= 1) m = fmaxf(m, __shfl_down(m, off, 64));
    __shared__ float sred[4];
    if (lane == 0) sred[wid] = m;
    __syncthreads();
    if (threadIdx.x == 0) {
        float bm = fmaxf(fmaxf(sred[0], sred[1]), fmaxf(sred[2], sred[3]));
        atomicMax(xmb, __float_as_int(bm));
    }
}

// ---------------- quantize weight -> ternary i8 (exact) ----------------

__global__ void quant_w(const float4* __restrict__ w4, int4x* __restrict__ wq,
                        const double* __restrict__ gsum) {
    double gamma = fmax(*gsum * (1.0 / (double)NW_ELEMS), 1e-4);
    double rg = 1.0 / gamma;
    int i = blockIdx.x * blockDim.x + threadIdx.x;   // 16 elems/thread
    signed char b[16];
    #pragma unroll
    for (int k = 0; k < 4; ++k) {
        float4 v = w4[4 * i + k];
        float vals[4] = {v.x, v.y, v.z, v.w};
        #pragma unroll
        for (int j = 0; j < 4; ++j) {
            float cv = fminf(fmaxf(vals[j], -2.0f), 2.0f);
            double t = rint((double)cv * rg);
            t = fmax(-1.0, fmin(1.0, t));
            b[4 * k + j] = (signed char)(int)t;
        }
    }
    int4x o;
    __builtin_memcpy(&o, b, 16);
    wq[i] = o;
}

// ---------------- quantize x -> i8 with scale 127/absmax ----------------

__global__ void quant_x(const float4* __restrict__ x4, int4x* __restrict__ xq,
                        const int* __restrict__ xmb) {
    const float s = 127.0f / __int_as_float(*xmb);
    int i = blockIdx.x * blockDim.x + threadIdx.x;   // 16 elems/thread
    signed char b[16];
    #pragma unroll
    for (int k = 0; k < 4; ++k) {
        float4 v = x4[4 * i + k];
        float vals[4] = {v.x, v.y, v.z, v.w};
        #pragma unroll
        for (int j = 0; j < 4; ++j) {
            int q = (int)rintf(vals[j] * s);
            q = max(-127, min(127, q));
            b[4 * k + j] = (signed char)q;
        }
    }
    int4x o;
    __builtin_memcpy(&o, b, 16);
    xq[i] = o;
}

// ---------------- 256x256 i8 GEMM, BK=128, R5 schedule ----------------
// 512 threads = 8 waves (2M x 4N). Per wave: 128x64 output = acc[8][4] i32x4.
// LDS byte layout IDENTICAL to the validated f16 kernel: A buf0 @0, A buf1
// @32768, B buf0 @65536, B buf1 @98304; row stride 128 B (now 128 i8 = BK),
// 8 slots x 16 B per row, XOR-swizzle slot^=(row&7) -> measured-zero conflicts.
// mfma_i32_16x16x64_i8: A-frag = 16 k-consecutive i8 = one b128; k-step 0 =
// slots kg, k-step 1 = slots 4|kg (same formula as the f16 version's s-bit).
// Per tile (128 k): 24 ds_read_b128 + 64 MFMA per wave; NT=32 tiles.
// Schedule per tile (validated R5 pattern, best measured):
//   win1: read b0(4),a1(8); Q0(a0xb0); read b1(4); Q1(a0xb1)
//   B1  : vmcnt(4)+lgkmcnt(0)+barrier   (A(t+1) resident for ALL waves)
//   win2: stage A(t+2); prefetch a0<-nxt(8); Q2(a1xb0); stage B(t+2); Q3(a1xb1)
//   B2  : vmcnt(8)+barrier              (B(t+1) resident for ALL waves)

__device__ inline void gload16(const char* g, char* lds) {
    __builtin_amdgcn_global_load_lds((const __attribute__((address_space(1))) void*)g,
        (__attribute__((address_space(3))) void*)lds, 16, 0, 0);
}

#define MFMAI8(a, b, c) __builtin_amdgcn_mfma_i32_16x16x64_i8(a, b, c, 0, 0, 0)

__global__ __launch_bounds__(512, 2) void gemm_kernel(
    const char* __restrict__ A,   // xq [M][K] i8
    const char* __restrict__ B,   // wq [N][K] i8
    const float* __restrict__ bias,
    const double* __restrict__ gsum,
    const int* __restrict__ xmb,
    float* __restrict__ out) {
    __shared__ __align__(16) char sm[131072];

    const int tid = threadIdx.x;
    const int wid = tid >> 6;
    const int lane = tid & 63;
    const int fr = lane & 15;
    const int kg = lane >> 4;
    const int f7 = fr & 7;
    const int wm = wid >> 2;   // 0..1
    const int wn = wid & 3;    // 0..3

    // T1: bijective XCD swizzle (2048 % 8 == 0).
    const int orig = blockIdx.x;
    const int bm = ((orig & 7) << 2) + ((orig >> 3) & 3);
    const int bn = orig >> 5;
    const int m0 = bm << 8, n0 = bn << 8;

    // staging: linear LDS dest, inverse-swizzled global source (rule #21)
    // thread covers row srow (128 B = full BK row), k-slot16 = (tid&7)^(srow&7)
    const int srow = tid >> 3;
    const int ks16 = (((tid & 7) ^ (srow & 7)) << 4);
    const int poff = srow * K_DIM + ks16;   // bytes (i8: elem == byte)
    const char* Ab = A + (size_t)m0 * K_DIM + poff;
    const char* Bb = B + (size_t)n0 * K_DIM + poff;
    const uint32_t dwave = (uint32_t)(wid << 10);

    #define STAGE_A(ktB, bufb) do {                                             \
        _Pragma("unroll")                                                       \
        for (int _i = 0; _i < 4; ++_i)                                          \
            gload16(Ab + (_i * (64 * K_DIM) + (ktB)),                           \
                    sm + (bufb) * 32768 + (_i << 13) + dwave);                  \
    } while (0)
    #define STAGE_B(ktB, bufb) do {                                             \
        _Pragma("unroll")                                                       \
        for (int _i = 0; _i < 4; ++_i)                                          \
            gload16(Bb + (_i * (64 * K_DIM) + (ktB)),                           \
                    sm + 65536 + (bufb) * 32768 + (_i << 13) + dwave);          \
    } while (0)

    // base pointers carrying the lane-dependent swizzle; all reads = base + imm
    const char* const smc = sm;
    const char* const pAk0 = smc + ((wm * 128 + fr) << 7) + ((kg ^ f7) << 4);
    const char* const pAk1 = smc + ((wm * 128 + fr) << 7) + (((4 | kg) ^ f7) << 4);
    const char* const pBk0 = smc + 65536 + ((wn * 64 + fr) << 7) + ((kg ^ f7) << 4);
    const char* const pBk1 = smc + 65536 + ((wn * 64 + fr) << 7) + (((4 | kg) ^ f7) << 4);

    int4x acc[8][4] = {};
    int4x a0[4][2], a1[4][2], b0[2][2], b1[2][2];

    // prologue: tile 0 -> buf0, tile 1 -> buf1; wait tile 0; prime a0 of tile 0
    STAGE_A(0, 0); STAGE_B(0, 0);
    STAGE_A(128, 1); STAGE_B(128, 1);
    asm volatile("s_waitcnt vmcnt(8)" ::: "memory");
    __builtin_amdgcn_s_barrier();
    asm volatile("" ::: "memory");
    __builtin_amdgcn_sched_barrier(0);
    #pragma unroll
    for (int i = 0; i < 4; ++i) {
        a0[i][0] = *(const int4x*)(pAk0 + i * 2048);
        a0[i][1] = *(const int4x*)(pAk1 + i * 2048);
    }

    #define TILE(T_, CUR_, NXT_) do {                                             \
        const int _kt2 = ((T_) + 2) << 7;                                         \
        const bool _st = ((T_) < NT - 2);                                         \
        const bool _rd = ((T_) < NT - 1);                                         \
        /* ---- win1: read b0, a1; Q0 = a0 x b0 ---- */                           \
        _Pragma("unroll")                                                         \
        for (int j = 0; j < 2; ++j) {                                             \
            b0[j][0] = *(const int4x*)(pBk0 + ((CUR_) * 32768 + j * 2048));       \
            b0[j][1] = *(const int4x*)(pBk1 + ((CUR_) * 32768 + j * 2048));       \
        }                                                                         \
        _Pragma("unroll")                                                         \
        for (int i = 0; i < 4; ++i) {                                             \
            a1[i][0] = *(const int4x*)(pAk0 + ((CUR_) * 32768 + (4 + i) * 2048)); \
            a1[i][1] = *(const int4x*)(pAk1 + ((CUR_) * 32768 + (4 + i) * 2048)); \
        }                                                                         \
        __builtin_amdgcn_s_setprio(1);                                            \
        _Pragma("unroll")                                                         \
        for (int i = 0; i < 4; ++i)                                               \
            _Pragma("unroll")                                                     \
            for (int j = 0; j < 2; ++j) {                                         \
                acc[i][j] = MFMAI8(a0[i][0], b0[j][0], acc[i][j]);                \
                acc[i][j] = MFMAI8(a0[i][1], b0[j][1], acc[i][j]);                \
            }                                                                     \
        __builtin_amdgcn_s_setprio(0);                                            \
        /* ---- read b1; Q1 = a0 x b1 ---- */                                     \
        _Pragma("unroll")                                                         \
        for (int j = 0; j < 2; ++j) {                                             \
            b1[j][0] = *(const int4x*)(pBk0 + ((CUR_) * 32768 + (2 + j) * 2048)); \
            b1[j][1] = *(const int4x*)(pBk1 + ((CUR_) * 32768 + (2 + j) * 2048)); \
        }                                                                         \
        __builtin_amdgcn_s_setprio(1);                                            \
        _Pragma("unroll")                                                         \
        for (int i = 0; i < 4; ++i)                                               \
            _Pragma("unroll")                                                     \
            for (int j = 0; j < 2; ++j) {                                         \
                acc[i][2 + j] = MFMAI8(a0[i][0], b1[j][0], acc[i][2 + j]);        \
                acc[i][2 + j] = MFMAI8(a0[i][1], b1[j][1], acc[i][2 + j]);        \
            }                                                                     \
        __builtin_amdgcn_s_setprio(0);                                            \
        /* ---- B1: buf[cur] reads drained; A(t+1) resident everywhere ---- */    \
        asm volatile("s_waitcnt vmcnt(4) lgkmcnt(0)" ::: "memory");               \
        __builtin_amdgcn_sched_barrier(0);                                        \
        __builtin_amdgcn_s_barrier();                                             \
        asm volatile("" ::: "memory");                                            \
        __builtin_amdgcn_sched_barrier(0);                                        \
        /* ---- win2: stage A(t+2); prefetch a0 <- nxt; Q2 = a1 x b0 ---- */      \
        if (_st) STAGE_A(_kt2, CUR_);                                             \
        if (_rd) {                                                                \
            _Pragma("unroll")                                                     \
            for (int i = 0; i < 4; ++i) {                                         \
                a0[i][0] = *(const int4x*)(pAk0 + ((NXT_) * 32768 + i * 2048));   \
                a0[i][1] = *(const int4x*)(pAk1 + ((NXT_) * 32768 + i * 2048));   \
            }                                                                     \
        }                                                                         \
        __builtin_amdgcn_s_setprio(1);                                            \
        _Pragma("unroll")                                                         \
        for (int i = 0; i < 4; ++i)                                               \
            _Pragma("unroll")                                                     \
            for (int j = 0; j < 2; ++j) {                                         \
                acc[4 + i][j] = MFMAI8(a1[i][0], b0[j][0], acc[4 + i][j]);        \
                acc[4 + i][j] = MFMAI8(a1[i][1], b0[j][1], acc[4 + i][j]);        \
            }                                                                     \
        __builtin_amdgcn_s_setprio(0);                                            \
        if (_st) STAGE_B(_kt2, CUR_);                                             \
        __builtin_amdgcn_s_setprio(1);                                            \
        _Pragma("unroll")                                                         \
        for (int i = 0; i < 4; ++i)                                               \
            _Pragma("unroll")                                                     \
            for (int j = 0; j < 2; ++j) {                                         \
                acc[4 + i][2 + j] = MFMAI8(a1[i][0], b1[j][0], acc[4 + i][2 + j]);\
                acc[4 + i][2 + j] = MFMAI8(a1[i][1], b1[j][1], acc[4 + i][2 + j]);\
            }                                                                     \
        __builtin_amdgcn_s_setprio(0);                                            \
        /* ---- B2: B(t+1) resident everywhere ---- */                            \
        if (_st) {                                                                \
            asm volatile("s_waitcnt vmcnt(8)" ::: "memory");                      \
        } else if ((T_) == NT - 2) {                                              \
            asm volatile("s_waitcnt vmcnt(0)" ::: "memory");                      \
        }                                                                         \
        __builtin_amdgcn_sched_barrier(0);                                        \
        __builtin_amdgcn_s_barrier();                                             \
        asm volatile("" ::: "memory");                                            \
        __builtin_amdgcn_sched_barrier(0);                                        \
    } while (0)

    for (int t = 0; t < NT; t += 2) {
        TILE(t, 0, 1);
        TILE(t + 1, 1, 0);
    }

    // ---- epilogue: out = acc * (gamma*xmax/127) + bias. C/D: col=fr, row=kg*4+jj ----
    const double gamma = fmax(*gsum * (1.0 / (double)NW_ELEMS), 1e-4);
    const float scale = (float)(gamma * (double)__int_as_float(*xmb) * (1.0 / 127.0));
    const int rbase = m0 + wm * 128 + (kg << 2);
    #pragma unroll
    for (int j = 0; j < 4; ++j) {
        const int gn = n0 + wn * 64 + j * 16 + fr;
        const float bv = bias[gn];
        #pragma unroll
        for (int i = 0; i < 8; ++i) {
            #pragma unroll
            for (int jj = 0; jj < 4; ++jj) {
                const int gm = rbase + i * 16 + jj;
                out[(size_t)gm * N_DIM + gn] = (float)acc[i][j][jj] * scale + bv;
            }
        }
    }
}

// ---------------- launch ----------------

extern "C" void kernel_launch(void* const* d_in, const int* in_sizes, int n_in,
                              void* d_out, int out_size, void* d_ws, size_t ws_size,
                              hipStream_t stream) {
    const float* x = (const float*)d_in[0];
    const float* w = (const float*)d_in[1];
    const float* bias = (const float*)d_in[2];
    float* out = (float*)d_out;

    char* ws = (char*)d_ws;
    double* gsum = (double*)ws;
    int* xmb = (int*)(ws + 8);
    char* xq = ws + 256;                                // 33.5 MB i8
    char* wq = ws + 256 + (size_t)NX_ELEMS;             // 64 MB i8

    zero_scalars<<<1, 1, 0, stream>>>(gsum, xmb);
    gamma_reduce<<<2048, 256, 0, stream>>>((const float4*)w, gsum, NW_ELEMS / 4);
    xmax_reduce<<<2048, 256, 0, stream>>>((const float4*)x, xmb, NX_ELEMS / 4);
    quant_w<<<NW_ELEMS / 16 / 256, 256, 0, stream>>>((const float4*)w, (int4x*)wq, gsum);
    quant_x<<<NX_ELEMS / 16 / 256, 256, 0, stream>>>((const float4*)x, (int4x*)xq, xmb);

    const int nblk = (M_DIM / 256) * (N_DIM / 256);   // 2048
    gemm_kernel<<<nblk, 512, 0, stream>>>(xq, wq, bias, gsum, xmb, out);
}